// Round 11
// baseline (239.323 us; speedup 1.0000x reference)
//
#include <hip/hip_runtime.h>

#define D_MODEL 768
#define N_HEADS 12
#define SEQ 4096
#define KVB 64

typedef __attribute__((ext_vector_type(4))) float f32x4;
typedef __attribute__((ext_vector_type(16))) float f32x16;
typedef __attribute__((ext_vector_type(8))) short bf16x8;   // 8 bf16 = 4 VGPRs
typedef __attribute__((ext_vector_type(4))) unsigned short u16x4;

typedef __attribute__((address_space(3))) void lds_void;
typedef __attribute__((address_space(1))) const void glb_void;

static __device__ __forceinline__ void gld_lds16(const void* g, void* l) {
    __builtin_amdgcn_global_load_lds((glb_void*)g, (lds_void*)l, 16, 0, 0);
}

static __device__ __forceinline__ unsigned short f32_bf16(float f) {
    union { float f; unsigned int u; } c; c.f = f;
    unsigned int u = c.u;
    u += 0x7FFFu + ((u >> 16) & 1u);   // round-to-nearest-even
    return (unsigned short)(u >> 16);
}

static __device__ __forceinline__ unsigned int cvtpk(float lo, float hi) {
    unsigned int r;
    asm("v_cvt_pk_bf16_f32 %0, %1, %2" : "=v"(r) : "v"(lo), "v"(hi));
    return r;
}

// ---------------- fp32 -> bf16 convert ----------------
__global__ void cvt_bf16(const float* __restrict__ in, unsigned short* __restrict__ out, int n) {
    int i = (blockIdx.x * blockDim.x + threadIdx.x) * 4;
    int stride = gridDim.x * blockDim.x * 4;
    for (; i < n; i += stride) {
        f32x4 v = *(const f32x4*)(in + i);
        u16x4 o;
        o[0] = f32_bf16(v[0]); o[1] = f32_bf16(v[1]);
        o[2] = f32_bf16(v[2]); o[3] = f32_bf16(v[3]);
        *(u16x4*)(out + i) = o;
    }
}

// Q scale: (1/8) * log2(e) folded in so attn uses raw v_exp_f32 (exp2)
#define QSCL 0.18033688f

// ---------------- QKV GEMM: gld_lds staging + swizzled LDS ----------------
// V^T stored with t permuted per 16-group (swap quad1<->quad2): makes attn's
// P->A-frag a straight register slice (no half-swap shfl).
__global__ __launch_bounds__(256) void qkv_gemm(const unsigned short* __restrict__ A,
                                                const unsigned short* __restrict__ Bw,
                                                unsigned short* __restrict__ qb,
                                                unsigned short* __restrict__ kb,
                                                unsigned short* __restrict__ vb) {
    __shared__ __attribute__((aligned(16))) unsigned short lA[128*32];
    __shared__ __attribute__((aligned(16))) unsigned short lB[128*32];
    const int K = 768;
    int tid = threadIdx.x;
    int wave = tid >> 6, lane = tid & 63;
    int qr = (wave >> 1) * 64, qc = (wave & 1) * 64;
    int m0 = blockIdx.x * 128, n0 = blockIdx.y * 128;
    f32x4 acc[4][4] = {};
    const int sl = (((lane >> 4) ^ (lane & 3)) * 16);   // read-side swizzled slot

    for (int kt = 0; kt < K; kt += 32) {
        __syncthreads();
        #pragma unroll
        for (int i = 0; i < 2; ++i) {
            int c = i*256 + tid;
            int row = c >> 2;
            int col = ((c & 3) ^ (row & 3)) * 8;        // pre-swizzled global source
            char* dA = (char*)lA + (i*256 + wave*64)*16;
            char* dB = (char*)lB + (i*256 + wave*64)*16;
            gld_lds16(A  + (size_t)(m0 + row) * K + kt + col, dA);
            gld_lds16(Bw + (size_t)(n0 + row) * K + kt + col, dB);
        }
        __syncthreads();
        bf16x8 af[4], bfr[4];
        #pragma unroll
        for (int m = 0; m < 4; ++m)
            af[m] = *(bf16x8*)((char*)lA + (qr + m*16 + (lane & 15))*64 + sl);
        #pragma unroll
        for (int n = 0; n < 4; ++n)
            bfr[n] = *(bf16x8*)((char*)lB + (qc + n*16 + (lane & 15))*64 + sl);
        #pragma unroll
        for (int m = 0; m < 4; ++m)
            #pragma unroll
            for (int n = 0; n < 4; ++n)
                acc[m][n] = __builtin_amdgcn_mfma_f32_16x16x32_bf16(af[m], bfr[n], acc[m][n], 0, 0, 0);
    }
    #pragma unroll
    for (int n = 0; n < 4; ++n) {
        int colg = n0 + qc + n*16 + (lane & 15);
        int s = colg / 768;
        int rem = colg - s * 768;
        int h = rem >> 6, d = rem & 63;
        if (s == 2) {
            #pragma unroll
            for (int m = 0; m < 4; ++m) {
                int rowb = m0 + qr + m*16 + (lane >> 4)*4;
                int bb = rowb >> 12, t0 = rowb & 4095;
                // sigma: swap quads 1<->2 within each 16-group (self-inverse)
                int t0p = (t0 & ~12) | ((t0 & 4) << 1) | ((t0 & 8) >> 1);
                u16x4 pk;
                #pragma unroll
                for (int r = 0; r < 4; ++r) pk[r] = f32_bf16(acc[m][n][r]);
                *(u16x4*)(vb + ((size_t)((bb*12 + h)*64 + d))*4096 + t0p) = pk;
            }
        } else {
            unsigned short* dst = (s == 0) ? qb : kb;
            float scl = (s == 0) ? QSCL : 1.0f;
            #pragma unroll
            for (int m = 0; m < 4; ++m) {
                int rowb = m0 + qr + m*16 + (lane >> 4)*4;
                #pragma unroll
                for (int r = 0; r < 4; ++r) {
                    int row = rowb + r;
                    int bb = row >> 12, t = row & 4095;
                    dst[((size_t)((bb*12 + h)*4096 + t))*64 + d] = f32_bf16(acc[m][n][r] * scl);
                }
            }
        }
    }
}

// ---------------- Flash attention: 8 waves = 4 wq x 2 wk, 3-buffer counted-vmcnt pipeline ----------------
__global__ __launch_bounds__(512, 4) void attn_kern(const unsigned short* __restrict__ qbuf,
                                                    const unsigned short* __restrict__ kbuf,
                                                    const unsigned short* __restrict__ vtbuf,
                                                    const int* __restrict__ mask,
                                                    unsigned short* __restrict__ ob) {
    __shared__ __attribute__((aligned(16))) char lds[3][16384];  // per buf: K frags 8KB, V frags 8KB
    __shared__ float lds_l[4][32];

    const int tid = threadIdx.x, wave = tid >> 6, lane = tid & 63;
    const int l31 = lane & 31, hi2 = lane >> 5;
    const int lane16 = lane * 16;
    const int wq = wave & 3, wk = wave >> 2;

    // XCD swizzle: 768 blocks -> 96 consecutive per XCD (3 bh each)
    int raw = blockIdx.x;
    int sb = (raw & 7) * 96 + (raw >> 3);
    int bh = sb >> 5, qi = sb & 31;
    int q0 = qi * 128;
    int b = bh / 12, h = bh - b*12;

    const unsigned short* Qb = qbuf + (size_t)bh * SEQ * 64;
    const unsigned short* Kb = kbuf + (size_t)bh * SEQ * 64;
    const unsigned short* Vt = vtbuf + (size_t)bh * 64 * SEQ;
    const int* mrow = mask + b * SEQ + wk*32 + l31;

    // Q B-frags: row = q0 + wq*32 + l31, d-elems = ds*16 + hi2*8 (Q pre-scaled by QSCL)
    bf16x8 bq[4];
    #pragma unroll
    for (int ds = 0; ds < 4; ++ds)
        bq[ds] = *(const bf16x8*)(Qb + (size_t)(q0 + wq*32 + l31)*64 + ds*16 + hi2*8);
    __builtin_amdgcn_sched_barrier(0);   // pin Q loads before staged loads (vmcnt counting)

    // B ones-vector for bias MFMA (t=0 only)
    union U4 { unsigned int w[4]; bf16x8 v; };
    U4 bext; bext.w[0] = (hi2 == 0) ? 0x3F80u : 0u; bext.w[1] = bext.w[2] = bext.w[3] = 0u;

    // stage one KV tile: 16 frag-major global_load_lds, 2 per wave (exactly 2 VMEM ops)
    auto stage = [&](char* buf, int kv0) {
        #pragma unroll
        for (int i = 0; i < 2; ++i) {
            int fi = wave*2 + i;
            const unsigned short* gsrc;
            if (fi < 8) {       // K frag (kt, ds)
                int kt = fi >> 2, ds = fi & 3;
                gsrc = Kb + (size_t)(kv0 + kt*32 + l31)*64 + ds*16 + hi2*8;
            } else {            // V frag (dt, ks) — t pre-permuted in global
                int g = fi - 8, dt = g >> 2, ks = g & 3;
                gsrc = Vt + (size_t)(dt*32 + l31)*4096 + kv0 + ks*16 + hi2*8;
            }
            gld_lds16(gsrc, buf + fi*1024);
        }
    };

    f32x16 oacc0 = {}, oacc1 = {};
    float lr = 0.0f;

    // rotating 3-buffer pointers (named, never dynamically indexed — rule 20)
    char* bA = lds[0];
    char* bB = lds[1];
    char* bC = lds[2];

    // prologue: stage tiles 0 and 1; per-wave VMEM order: [stage0 x2, m0, stage1 x2, m1]
    stage(bA, 0);
    int mb0 = mrow[0];
    stage(bB, KVB);
    int mb1 = mrow[KVB];
    asm volatile("s_waitcnt vmcnt(3)" ::: "memory");  // tile0 + m0 landed; tile1 in flight
    __builtin_amdgcn_sched_barrier(0);
    __builtin_amdgcn_s_barrier();
    __builtin_amdgcn_sched_barrier(0);

    const int NT = SEQ / KVB;
    for (int t = 0; t < NT; ++t) {
        int mb2 = 0;
        if (t + 2 < NT) {
            stage(bC, (t + 2) * KVB);       // 2 gld_lds
            mb2 = mrow[(t + 2) * KVB];      // 1 vector load  => 3 VMEM/iter
        }
        char* bufK = bA;
        char* bufV = bA + 8192;

        // ---- S^T = K . Q^T + bias (masked -1024, unmasked -17.25; exp2 fixed rebase) ----
        U4 ab;
        ab.w[0] = (hi2 == 0) ? (mb0 ? 0xC480u : 0xC18Au) : 0u;
        ab.w[1] = ab.w[2] = ab.w[3] = 0u;

        f32x16 s = {};
        s = __builtin_amdgcn_mfma_f32_32x32x16_bf16(ab.v, bext.v, s, 0, 0, 0);
        #pragma unroll
        for (int ds = 0; ds < 4; ++ds) {
            bf16x8 aK = *(bf16x8*)(bufK + (wk*4 + ds)*1024 + lane16);
            s = __builtin_amdgcn_mfma_f32_32x32x16_bf16(aK, bq[ds], s, 0, 0, 0);
        }

        // ---- P = exp2(s) via raw v_exp_f32 ----
        float rs = 0.0f;
        #pragma unroll
        for (int i = 0; i < 16; ++i) { s[i] = __builtin_amdgcn_exp2f(s[i]); rs += s[i]; }
        rs += __shfl_xor(rs, 32);
        lr += rs;

        // ---- P -> A-frags: straight register slice (V k-rows pre-permuted) ----
        bf16x8 pa[2];
        #pragma unroll
        for (int ks = 0; ks < 2; ++ks) {
            U4 w;
            w.w[0] = cvtpk(s[8*ks+0], s[8*ks+1]);
            w.w[1] = cvtpk(s[8*ks+2], s[8*ks+3]);
            w.w[2] = cvtpk(s[8*ks+4], s[8*ks+5]);
            w.w[3] = cvtpk(s[8*ks+6], s[8*ks+7]);
            pa[ks] = w.v;
        }

        // ---- O += P V (this wave's k-half) ----
        #pragma unroll
        for (int sb2 = 0; sb2 < 2; ++sb2) {
            int ksg = wk*2 + sb2;
            bf16x8 bv0 = *(bf16x8*)(bufV + (0*4 + ksg)*1024 + lane16);
            bf16x8 bv1 = *(bf16x8*)(bufV + (1*4 + ksg)*1024 + lane16);
            oacc0 = __builtin_amdgcn_mfma_f32_32x32x16_bf16(pa[sb2], bv0, oacc0, 0, 0, 0);
            oacc1 = __builtin_amdgcn_mfma_f32_32x32x16_bf16(pa[sb2], bv1, oacc1, 0, 0, 0);
        }

        // ---- counted-vmcnt barrier: tile t+1 staged; tile t+2 stays in flight ----
        if (t + 2 < NT) {
            asm volatile("s_waitcnt vmcnt(3)" ::: "memory");
        } else {
            asm volatile("s_waitcnt vmcnt(0)" ::: "memory");
        }
        __builtin_amdgcn_sched_barrier(0);
        __builtin_amdgcn_s_barrier();
        __builtin_amdgcn_sched_barrier(0);

        char* tmp = bA; bA = bB; bB = bC; bC = tmp;
        mb0 = mb1; mb1 = mb2;
    }

    // ---- combine wave pairs (fixed-M => pure sum); l is REG-indexed by q (R4 lesson) ----
    float* cbase = (float*)lds + wq * 2048;   // 32 regs x 64 lanes per wq
    if (wk == 1) {
        #pragma unroll
        for (int i = 0; i < 16; ++i) {
            cbase[i*64 + lane]        = oacc0[i];
            cbase[(16 + i)*64 + lane] = oacc1[i];
        }
        if (lane < 32) lds_l[wq][lane] = lr;
    }
    __syncthreads();
    if (wk == 0 && lane < 32) lds_l[wq][lane] += lr;   // lds_l[wq][q] = total row-sum
    __syncthreads();
    if (wk == 0) {
        #pragma unroll
        for (int r = 0; r < 16; ++r) {
            int q = (r & 3) + 8*(r >> 2) + 4*hi2;
            float inv = 1.0f / lds_l[wq][q];
            int tg = q0 + wq*32 + q;
            size_t base = ((size_t)(b*SEQ + tg)) * D_MODEL + h*64 + l31;
            ob[base]      = f32_bf16((oacc0[r] + cbase[r*64 + lane])        * inv);
            ob[base + 32] = f32_bf16((oacc1[r] + cbase[(16 + r)*64 + lane]) * inv);
        }
    }
}

// ---------------- Proj GEMM: gld_lds staging + swizzled LDS ----------------
__global__ __launch_bounds__(256) void proj_gemm(const unsigned short* __restrict__ A,
                                                 const unsigned short* __restrict__ Bw,
                                                 const float* __restrict__ bias,
                                                 float* __restrict__ out) {
    __shared__ __attribute__((aligned(16))) unsigned short lA[128*32];
    __shared__ __attribute__((aligned(16))) unsigned short lB[128*32];
    const int K = 768;
    int tid = threadIdx.x;
    int wave = tid >> 6, lane = tid & 63;
    int qr = (wave >> 1) * 64, qc = (wave & 1) * 64;
    int m0 = blockIdx.x * 128, n0 = blockIdx.y * 128;
    f32x4 acc[4][4] = {};
    const int sl = (((lane >> 4) ^ (lane & 3)) * 16);

    for (int kt = 0; kt < K; kt += 32) {
        __syncthreads();
        #pragma unroll
        for (int i = 0; i < 2; ++i) {
            int c = i*256 + tid;
            int row = c >> 2;
            int col = ((c & 3) ^ (row & 3)) * 8;
            char* dA = (char*)lA + (i*256 + wave*64)*16;
            char* dB = (char*)lB + (i*256 + wave*64)*16;
            gld_lds16(A  + (size_t)(m0 + row) * K + kt + col, dA);
            gld_lds16(Bw + (size_t)(n0 + row) * K + kt + col, dB);
        }
        __syncthreads();
        bf16x8 af[4], bfr[4];
        #pragma unroll
        for (int m = 0; m < 4; ++m)
            af[m] = *(bf16x8*)((char*)lA + (qr + m*16 + (lane & 15))*64 + sl);
        #pragma unroll
        for (int n = 0; n < 4; ++n)
            bfr[n] = *(bf16x8*)((char*)lB + (qc + n*16 + (lane & 15))*64 + sl);
        #pragma unroll
        for (int m = 0; m < 4; ++m)
            #pragma unroll
            for (int n = 0; n < 4; ++n)
                acc[m][n] = __builtin_amdgcn_mfma_f32_16x16x32_bf16(af[m], bfr[n], acc[m][n], 0, 0, 0);
    }
    #pragma unroll
    for (int n = 0; n < 4; ++n) {
        int colg = n0 + qc + n*16 + (lane & 15);
        float bn = bias[colg];
        #pragma unroll
        for (int m = 0; m < 4; ++m) {
            int rowb = m0 + qr + m*16 + (lane >> 4)*4;
            #pragma unroll
            for (int r = 0; r < 4; ++r)
                out[(size_t)(rowb + r) * 768 + colg] = acc[m][n][r] + bn;
        }
    }
}

extern "C" void kernel_launch(void* const* d_in, const int* in_sizes, int n_in,
                              void* d_out, int out_size, void* d_ws, size_t ws_size,
                              hipStream_t stream) {
    const float* x      = (const float*)d_in[0];
    const int*   mask   = (const int*)d_in[1];
    const float* w_qkv  = (const float*)d_in[2];
    const float* w_proj = (const float*)d_in[3];
    const float* b_proj = (const float*)d_in[4];
    float* out = (float*)d_out;

    unsigned short* ws = (unsigned short*)d_ws;
    unsigned short* xb     = ws;                    // 6291456
    unsigned short* wqkvb  = xb     + 6291456;      // 1769472
    unsigned short* wprojb = wqkvb  + 1769472;      // 589824
    unsigned short* qb     = wprojb + 589824;       // 6291456
    unsigned short* kb     = qb     + 6291456;
    unsigned short* vtb    = kb     + 6291456;      // V^T [B,H,64,T], t sigma-permuted
    unsigned short* ob     = vtb    + 6291456;      // 6291456

    cvt_bf16<<<1024, 256, 0, stream>>>(x,      xb,     6291456);
    cvt_bf16<<<256,  256, 0, stream>>>(w_qkv,  wqkvb,  1769472);
    cvt_bf16<<<128,  256, 0, stream>>>(w_proj, wprojb, 589824);

    qkv_gemm<<<dim3(64, 18), 256, 0, stream>>>(xb, wqkvb, qb, kb, vtb);
    attn_kern<<<768, 512, 0, stream>>>(qb, kb, vtb, mask, ob);
    proj_gemm<<<dim3(64, 6), 256, 0, stream>>>(ob, wprojb, b_proj, out);
}

// Round 12
// 217.207 us; speedup vs baseline: 1.1018x; 1.1018x over previous
//
#include <hip/hip_runtime.h>

#define D_MODEL 768
#define N_HEADS 12
#define SEQ 4096
#define KVB 64

typedef __attribute__((ext_vector_type(4))) float f32x4;
typedef __attribute__((ext_vector_type(16))) float f32x16;
typedef __attribute__((ext_vector_type(8))) short bf16x8;   // 8 bf16 = 4 VGPRs
typedef __attribute__((ext_vector_type(4))) unsigned short u16x4;

typedef __attribute__((address_space(3))) void lds_void;
typedef __attribute__((address_space(1))) const void glb_void;

static __device__ __forceinline__ void gld_lds16(const void* g, void* l) {
    __builtin_amdgcn_global_load_lds((glb_void*)g, (lds_void*)l, 16, 0, 0);
}

static __device__ __forceinline__ unsigned short f32_bf16(float f) {
    union { float f; unsigned int u; } c; c.f = f;
    unsigned int u = c.u;
    u += 0x7FFFu + ((u >> 16) & 1u);   // round-to-nearest-even
    return (unsigned short)(u >> 16);
}

static __device__ __forceinline__ unsigned int cvtpk(float lo, float hi) {
    unsigned int r;
    asm("v_cvt_pk_bf16_f32 %0, %1, %2" : "=v"(r) : "v"(lo), "v"(hi));
    return r;
}

// ---------------- fp32 -> bf16 convert ----------------
__global__ void cvt_bf16(const float* __restrict__ in, unsigned short* __restrict__ out, int n) {
    int i = (blockIdx.x * blockDim.x + threadIdx.x) * 4;
    int stride = gridDim.x * blockDim.x * 4;
    for (; i < n; i += stride) {
        f32x4 v = *(const f32x4*)(in + i);
        u16x4 o;
        o[0] = f32_bf16(v[0]); o[1] = f32_bf16(v[1]);
        o[2] = f32_bf16(v[2]); o[3] = f32_bf16(v[3]);
        *(u16x4*)(out + i) = o;
    }
}

// Q scale: (1/8) * log2(e) folded in so attn uses raw v_exp_f32 (exp2)
#define QSCL 0.18033688f

// ---------------- QKV GEMM: gld_lds staging + swizzled LDS ----------------
// V^T stored with t permuted per 16-group (swap quad1<->quad2): makes attn's
// P->A-frag a straight register slice (no half-swap shfl).
__global__ __launch_bounds__(256) void qkv_gemm(const unsigned short* __restrict__ A,
                                                const unsigned short* __restrict__ Bw,
                                                unsigned short* __restrict__ qb,
                                                unsigned short* __restrict__ kb,
                                                unsigned short* __restrict__ vb) {
    __shared__ __attribute__((aligned(16))) unsigned short lA[128*32];
    __shared__ __attribute__((aligned(16))) unsigned short lB[128*32];
    const int K = 768;
    int tid = threadIdx.x;
    int wave = tid >> 6, lane = tid & 63;
    int qr = (wave >> 1) * 64, qc = (wave & 1) * 64;
    int m0 = blockIdx.x * 128, n0 = blockIdx.y * 128;
    f32x4 acc[4][4] = {};
    const int sl = (((lane >> 4) ^ (lane & 3)) * 16);   // read-side swizzled slot

    for (int kt = 0; kt < K; kt += 32) {
        __syncthreads();
        #pragma unroll
        for (int i = 0; i < 2; ++i) {
            int c = i*256 + tid;
            int row = c >> 2;
            int col = ((c & 3) ^ (row & 3)) * 8;        // pre-swizzled global source
            char* dA = (char*)lA + (i*256 + wave*64)*16;
            char* dB = (char*)lB + (i*256 + wave*64)*16;
            gld_lds16(A  + (size_t)(m0 + row) * K + kt + col, dA);
            gld_lds16(Bw + (size_t)(n0 + row) * K + kt + col, dB);
        }
        __syncthreads();
        bf16x8 af[4], bfr[4];
        #pragma unroll
        for (int m = 0; m < 4; ++m)
            af[m] = *(bf16x8*)((char*)lA + (qr + m*16 + (lane & 15))*64 + sl);
        #pragma unroll
        for (int n = 0; n < 4; ++n)
            bfr[n] = *(bf16x8*)((char*)lB + (qc + n*16 + (lane & 15))*64 + sl);
        #pragma unroll
        for (int m = 0; m < 4; ++m)
            #pragma unroll
            for (int n = 0; n < 4; ++n)
                acc[m][n] = __builtin_amdgcn_mfma_f32_16x16x32_bf16(af[m], bfr[n], acc[m][n], 0, 0, 0);
    }
    #pragma unroll
    for (int n = 0; n < 4; ++n) {
        int colg = n0 + qc + n*16 + (lane & 15);
        int s = colg / 768;
        int rem = colg - s * 768;
        int h = rem >> 6, d = rem & 63;
        if (s == 2) {
            #pragma unroll
            for (int m = 0; m < 4; ++m) {
                int rowb = m0 + qr + m*16 + (lane >> 4)*4;
                int bb = rowb >> 12, t0 = rowb & 4095;
                // sigma: swap quads 1<->2 within each 16-group (self-inverse)
                int t0p = (t0 & ~12) | ((t0 & 4) << 1) | ((t0 & 8) >> 1);
                u16x4 pk;
                #pragma unroll
                for (int r = 0; r < 4; ++r) pk[r] = f32_bf16(acc[m][n][r]);
                *(u16x4*)(vb + ((size_t)((bb*12 + h)*64 + d))*4096 + t0p) = pk;
            }
        } else {
            unsigned short* dst = (s == 0) ? qb : kb;
            float scl = (s == 0) ? QSCL : 1.0f;
            #pragma unroll
            for (int m = 0; m < 4; ++m) {
                int rowb = m0 + qr + m*16 + (lane >> 4)*4;
                #pragma unroll
                for (int r = 0; r < 4; ++r) {
                    int row = rowb + r;
                    int bb = row >> 12, t = row & 4095;
                    dst[((size_t)((bb*12 + h)*4096 + t))*64 + d] = f32_bf16(acc[m][n][r] * scl);
                }
            }
        }
    }
}

// ---------------- Flash attention: 8 waves = 4 wq x 2 wk, T15 2-deep S pipeline ----------------
// Per tile iter: QK(t+1) MFMAs issue first; softmax(t) VALU runs under their latency; PV(t).
__global__ __launch_bounds__(512, 4) void attn_kern(const unsigned short* __restrict__ qbuf,
                                                    const unsigned short* __restrict__ kbuf,
                                                    const unsigned short* __restrict__ vtbuf,
                                                    const int* __restrict__ mask,
                                                    unsigned short* __restrict__ ob) {
    __shared__ __attribute__((aligned(16))) char lds[3][16384];  // per buf: K frags 8KB, V frags 8KB
    __shared__ float lds_l[4][32];

    const int tid = threadIdx.x, wave = tid >> 6, lane = tid & 63;
    const int l31 = lane & 31, hi2 = lane >> 5;
    const int lane16 = lane * 16;
    const int wq = wave & 3, wk = wave >> 2;

    // XCD swizzle: 768 blocks -> 96 consecutive per XCD (3 bh each)
    int raw = blockIdx.x;
    int sb = (raw & 7) * 96 + (raw >> 3);
    int bh = sb >> 5, qi = sb & 31;
    int q0 = qi * 128;
    int b = bh / 12, h = bh - b*12;

    const unsigned short* Qb = qbuf + (size_t)bh * SEQ * 64;
    const unsigned short* Kb = kbuf + (size_t)bh * SEQ * 64;
    const unsigned short* Vt = vtbuf + (size_t)bh * 64 * SEQ;
    const int* mrow = mask + b * SEQ + wk*32 + l31;

    // Q B-frags: row = q0 + wq*32 + l31, d-elems = ds*16 + hi2*8 (Q pre-scaled by QSCL)
    bf16x8 bq[4];
    #pragma unroll
    for (int ds = 0; ds < 4; ++ds)
        bq[ds] = *(const bf16x8*)(Qb + (size_t)(q0 + wq*32 + l31)*64 + ds*16 + hi2*8);
    __builtin_amdgcn_sched_barrier(0);   // pin Q loads before staged loads (vmcnt counting)

    // B ones-vector for bias MFMA (t=0 only)
    union U4 { unsigned int w[4]; bf16x8 v; };
    U4 bext; bext.w[0] = (hi2 == 0) ? 0x3F80u : 0u; bext.w[1] = bext.w[2] = bext.w[3] = 0u;

    // stage one KV tile: 16 frag-major global_load_lds, 2 per wave (exactly 2 VMEM ops)
    auto stage = [&](char* buf, int kv0) {
        #pragma unroll
        for (int i = 0; i < 2; ++i) {
            int fi = wave*2 + i;
            const unsigned short* gsrc;
            if (fi < 8) {       // K frag (kt, ds)
                int kt = fi >> 2, ds = fi & 3;
                gsrc = Kb + (size_t)(kv0 + kt*32 + l31)*64 + ds*16 + hi2*8;
            } else {            // V frag (dt, ks) — t pre-permuted in global
                int g = fi - 8, dt = g >> 2, ks = g & 3;
                gsrc = Vt + (size_t)(dt*32 + l31)*4096 + kv0 + ks*16 + hi2*8;
            }
            gld_lds16(gsrc, buf + fi*1024);
        }
    };

    f32x16 oacc0 = {}, oacc1 = {};
    float lr = 0.0f;

    // QK(tile) into fresh accumulator: bias MFMA as C-init, then 4 chained K-MFMAs
    auto QK = [&](const char* bufK, int mb) -> f32x16 {
        U4 ab;
        ab.w[0] = (hi2 == 0) ? (mb ? 0xC480u : 0xC18Au) : 0u;
        ab.w[1] = ab.w[2] = ab.w[3] = 0u;
        f32x16 s = {};
        s = __builtin_amdgcn_mfma_f32_32x32x16_bf16(ab.v, bext.v, s, 0, 0, 0);
        #pragma unroll
        for (int ds = 0; ds < 4; ++ds) {
            bf16x8 aK = *(bf16x8*)(bufK + (wk*4 + ds)*1024 + lane16);
            s = __builtin_amdgcn_mfma_f32_32x32x16_bf16(aK, bq[ds], s, 0, 0, 0);
        }
        return s;
    };

    // softmax + PV for one tile (consumes s by value)
    auto SMPV = [&](f32x16 s, const char* bufV) {
        float rs = 0.0f;
        #pragma unroll
        for (int i = 0; i < 16; ++i) { s[i] = __builtin_amdgcn_exp2f(s[i]); rs += s[i]; }
        rs += __shfl_xor(rs, 32);
        lr += rs;
        bf16x8 pa[2];
        #pragma unroll
        for (int ks = 0; ks < 2; ++ks) {
            U4 w;
            w.w[0] = cvtpk(s[8*ks+0], s[8*ks+1]);
            w.w[1] = cvtpk(s[8*ks+2], s[8*ks+3]);
            w.w[2] = cvtpk(s[8*ks+4], s[8*ks+5]);
            w.w[3] = cvtpk(s[8*ks+6], s[8*ks+7]);
            pa[ks] = w.v;
        }
        #pragma unroll
        for (int sb2 = 0; sb2 < 2; ++sb2) {
            int ksg = wk*2 + sb2;
            bf16x8 bv0 = *(bf16x8*)(bufV + (0*4 + ksg)*1024 + lane16);
            bf16x8 bv1 = *(bf16x8*)(bufV + (1*4 + ksg)*1024 + lane16);
            oacc0 = __builtin_amdgcn_mfma_f32_32x32x16_bf16(pa[sb2], bv0, oacc0, 0, 0, 0);
            oacc1 = __builtin_amdgcn_mfma_f32_32x32x16_bf16(pa[sb2], bv1, oacc1, 0, 0, 0);
        }
    };

    // rotating 3-buffer pointers (named, never dynamically indexed — rule 20)
    char* bA = lds[0];
    char* bB = lds[1];
    char* bC = lds[2];

    // prologue: stage tiles 0 and 1; drain; barrier; compute QK(0)
    stage(bA, 0);
    stage(bB, KVB);
    int mb1 = mrow[KVB];
    int mb0 = mrow[0];
    asm volatile("s_waitcnt vmcnt(0)" ::: "memory");
    __builtin_amdgcn_sched_barrier(0);
    __builtin_amdgcn_s_barrier();
    __builtin_amdgcn_sched_barrier(0);
    f32x16 sA = QK(bA, mb0);

    const int NT = SEQ / KVB;
    for (int t = 0; t < NT; ++t) {
        int mb2 = 0;
        if (t + 2 < NT) {
            stage(bC, (t + 2) * KVB);       // 2 gld_lds
            mb2 = mrow[(t + 2) * KVB];      // 1 vector load
        }

        // ---- QK(t+1) first: its MFMA latency is hidden by softmax(t)'s VALU ----
        f32x16 sB;
        if (t + 1 < NT) sB = QK(bB, mb1);

        // ---- softmax(t) + PV(t) ----
        SMPV(sA, bA + 8192);

        // ---- drain + barrier: tile t+2 landed in bC; bA safe to rewrite next iter ----
        asm volatile("s_waitcnt vmcnt(0)" ::: "memory");
        __builtin_amdgcn_sched_barrier(0);
        __builtin_amdgcn_s_barrier();
        __builtin_amdgcn_sched_barrier(0);

        if (t + 1 < NT) sA = sB;            // 2-deep handoff (16 v_mov)
        char* tmp = bA; bA = bB; bB = bC; bC = tmp;
        mb1 = mb2;
    }

    // ---- combine wave pairs (fixed-M => pure sum); l is REG-indexed by q (R4 lesson) ----
    float* cbase = (float*)lds + wq * 2048;   // 32 regs x 64 lanes per wq
    if (wk == 1) {
        #pragma unroll
        for (int i = 0; i < 16; ++i) {
            cbase[i*64 + lane]        = oacc0[i];
            cbase[(16 + i)*64 + lane] = oacc1[i];
        }
        if (lane < 32) lds_l[wq][lane] = lr;
    }
    __syncthreads();
    if (wk == 0 && lane < 32) lds_l[wq][lane] += lr;   // lds_l[wq][q] = total row-sum
    __syncthreads();
    if (wk == 0) {
        #pragma unroll
        for (int r = 0; r < 16; ++r) {
            int q = (r & 3) + 8*(r >> 2) + 4*hi2;
            float inv = 1.0f / lds_l[wq][q];
            int tg = q0 + wq*32 + q;
            size_t base = ((size_t)(b*SEQ + tg)) * D_MODEL + h*64 + l31;
            ob[base]      = f32_bf16((oacc0[r] + cbase[r*64 + lane])        * inv);
            ob[base + 32] = f32_bf16((oacc1[r] + cbase[(16 + r)*64 + lane]) * inv);
        }
    }
}

// ---------------- Proj GEMM: gld_lds staging + swizzled LDS ----------------
__global__ __launch_bounds__(256) void proj_gemm(const unsigned short* __restrict__ A,
                                                 const unsigned short* __restrict__ Bw,
                                                 const float* __restrict__ bias,
                                                 float* __restrict__ out) {
    __shared__ __attribute__((aligned(16))) unsigned short lA[128*32];
    __shared__ __attribute__((aligned(16))) unsigned short lB[128*32];
    const int K = 768;
    int tid = threadIdx.x;
    int wave = tid >> 6, lane = tid & 63;
    int qr = (wave >> 1) * 64, qc = (wave & 1) * 64;
    int m0 = blockIdx.x * 128, n0 = blockIdx.y * 128;
    f32x4 acc[4][4] = {};
    const int sl = (((lane >> 4) ^ (lane & 3)) * 16);

    for (int kt = 0; kt < K; kt += 32) {
        __syncthreads();
        #pragma unroll
        for (int i = 0; i < 2; ++i) {
            int c = i*256 + tid;
            int row = c >> 2;
            int col = ((c & 3) ^ (row & 3)) * 8;
            char* dA = (char*)lA + (i*256 + wave*64)*16;
            char* dB = (char*)lB + (i*256 + wave*64)*16;
            gld_lds16(A  + (size_t)(m0 + row) * K + kt + col, dA);
            gld_lds16(Bw + (size_t)(n0 + row) * K + kt + col, dB);
        }
        __syncthreads();
        bf16x8 af[4], bfr[4];
        #pragma unroll
        for (int m = 0; m < 4; ++m)
            af[m] = *(bf16x8*)((char*)lA + (qr + m*16 + (lane & 15))*64 + sl);
        #pragma unroll
        for (int n = 0; n < 4; ++n)
            bfr[n] = *(bf16x8*)((char*)lB + (qc + n*16 + (lane & 15))*64 + sl);
        #pragma unroll
        for (int m = 0; m < 4; ++m)
            #pragma unroll
            for (int n = 0; n < 4; ++n)
                acc[m][n] = __builtin_amdgcn_mfma_f32_16x16x32_bf16(af[m], bfr[n], acc[m][n], 0, 0, 0);
    }
    #pragma unroll
    for (int n = 0; n < 4; ++n) {
        int colg = n0 + qc + n*16 + (lane & 15);
        float bn = bias[colg];
        #pragma unroll
        for (int m = 0; m < 4; ++m) {
            int rowb = m0 + qr + m*16 + (lane >> 4)*4;
            #pragma unroll
            for (int r = 0; r < 4; ++r)
                out[(size_t)(rowb + r) * 768 + colg] = acc[m][n][r] + bn;
        }
    }
}

extern "C" void kernel_launch(void* const* d_in, const int* in_sizes, int n_in,
                              void* d_out, int out_size, void* d_ws, size_t ws_size,
                              hipStream_t stream) {
    const float* x      = (const float*)d_in[0];
    const int*   mask   = (const int*)d_in[1];
    const float* w_qkv  = (const float*)d_in[2];
    const float* w_proj = (const float*)d_in[3];
    const float* b_proj = (const float*)d_in[4];
    float* out = (float*)d_out;

    unsigned short* ws = (unsigned short*)d_ws;
    unsigned short* xb     = ws;                    // 6291456
    unsigned short* wqkvb  = xb     + 6291456;      // 1769472
    unsigned short* wprojb = wqkvb  + 1769472;      // 589824
    unsigned short* qb     = wprojb + 589824;       // 6291456
    unsigned short* kb     = qb     + 6291456;
    unsigned short* vtb    = kb     + 6291456;      // V^T [B,H,64,T], t sigma-permuted
    unsigned short* ob     = vtb    + 6291456;      // 6291456

    cvt_bf16<<<1024, 256, 0, stream>>>(x,      xb,     6291456);
    cvt_bf16<<<256,  256, 0, stream>>>(w_qkv,  wqkvb,  1769472);
    cvt_bf16<<<128,  256, 0, stream>>>(w_proj, wprojb, 589824);

    qkv_gemm<<<dim3(64, 18), 256, 0, stream>>>(xb, wqkvb, qb, kb, vtb);
    attn_kern<<<768, 512, 0, stream>>>(qb, kb, vtb, mask, ob);
    proj_gemm<<<dim3(64, 6), 256, 0, stream>>>(ob, wprojb, b_proj, out);
}